// Round 10
// baseline (148.338 us; speedup 1.0000x reference)
//
#include <hip/hip_runtime.h>
#include <hip/hip_bf16.h>

typedef __attribute__((ext_vector_type(4))) float f32x4;
typedef __attribute__((ext_vector_type(8))) short s16x8;

static constexpr int Bn = 32;
static constexpr int Tn = 4096;
static constexpr int Dn = 256;
static constexpr int Un = 256;
static constexpr int NBLK = 64;   // blocks per batch; block owns 64 t-rows = 2 strips of 32

// fp32 -> bf16 round-to-nearest-even (prep only)
__device__ __forceinline__ ushort f2bf(float f) {
    unsigned x = __float_as_uint(f);
    x += 0x7fffu + ((x >> 16) & 1u);
    return (ushort)(x >> 16);
}

// HW packed fp32->bf16 (RTNE)
__device__ __forceinline__ unsigned cvt_pk_bf16(float a, float b) {
    unsigned r;
    asm("v_cvt_pk_bf16_f32 %0, %1, %2" : "=v"(r) : "v"(a), "v"(b));
    return r;
}

// stable fast tanh
__device__ __forceinline__ float fast_tanh(float x) {
    float ax = fabsf(x);
    float e = __expf(-2.0f * ax);
    float r = __fdividef(1.0f - e, 1.0f + e);
    return copysignf(r, x);
}

// K0: prep. Blocks 0..255: W1T[u][d] = bf16(W1[d][u]). Blocks 256..287: qproj.
__global__ __launch_bounds__(256) void k_prep(const float* __restrict__ W1,
                                              ushort* __restrict__ W1T,
                                              const float* __restrict__ query,
                                              const float* __restrict__ W2,
                                              const float* __restrict__ b1,
                                              const float* __restrict__ b2,
                                              float* __restrict__ qb) {
    __shared__ float qs[Dn];
    if (blockIdx.x < 256) {
        const int u = blockIdx.x, d = threadIdx.x;
        W1T[u * Dn + d] = f2bf(W1[d * Un + u]);
    } else {
        const int b = blockIdx.x - 256, u = threadIdx.x;
        qs[u] = query[b * Dn + u];
        __syncthreads();
        float acc = b1[u] + b2[u];
        #pragma unroll 8
        for (int d = 0; d < Dn; ++d) acc += qs[d] * W2[d * Un + u];
        qb[b * Un + u] = acc;
    }
}

// K1: barrier-free-core fused GEMM + flash. Block = 64t x 256u, 4 waves
// u-split (64u each). A-fragments load DIRECTLY from global (two dwordx4 per
// 16x32 tile, line-granular), cvt_pk in-register — NO LDS staging, NO k-loop
// barriers: loads stream continuously, latency hidden by TLP (k_ctx_partial
// pattern, 9 TB/s proven). B ring depth-1 from L2-hot W1T. 3 barriers per
// 32-row strip (epilogue only). LDS ~5 KB, VGPR ~140.
__global__ __launch_bounds__(256, 3) void k_main(const float* __restrict__ values,
                                                 const ushort* __restrict__ W1T,
                                                 const float* __restrict__ qb,
                                                 const float* __restrict__ Vw,
                                                 const float* __restrict__ bV,
                                                 float* __restrict__ scores,
                                                 float* __restrict__ pM,
                                                 float* __restrict__ pS,
                                                 float* __restrict__ pctx) {
    __shared__ float sred[4][32];
    __shared__ float slp[32];
    __shared__ float sfac[2];
    __shared__ float runMS[2];
    __shared__ f32x4 cred[4][64];

    const int tid = threadIdx.x;
    const int b = blockIdx.y, blk = blockIdx.x;
    const int wid = tid >> 6, lane = tid & 63;
    const int l15 = lane & 15, hi = lane >> 4;
    const int uofs = wid * 64;

    // B base pointers for this lane's 4 u-tiles
    const ushort* wb[4];
    #pragma unroll
    for (int ut = 0; ut < 4; ++ut)
        wb[ut] = W1T + (size_t)(uofs + ut * 16 + l15) * Dn + hi * 8;

    float Vreg[4], qreg[4];
    #pragma unroll
    for (int ut = 0; ut < 4; ++ut) {
        int u = uofs + ut * 16 + l15;
        Vreg[ut] = Vw[u];
        qreg[ut] = qb[b * Un + u];
    }
    const float bv = bV[0];

    if (tid == 0) { runMS[0] = -1e30f; runMS[1] = 0.f; }

    f32x4 cacc = (f32x4){0.f, 0.f, 0.f, 0.f};

    #pragma unroll 1
    for (int ck = 0; ck < 2; ++ck) {
        const int t0 = blk * 64 + ck * 32;
        const float* arow = values + ((size_t)b * Tn + t0) * Dn;
        // per-lane A base: row (tt*16 + l15), cols kc*32 + hi*8
        const float* a0 = arow + (size_t)l15 * Dn + hi * 8;         // tt=0
        const float* a1 = arow + (size_t)(16 + l15) * Dn + hi * 8;  // tt=1

        f32x4 acc[2][4];
        #pragma unroll
        for (int tt = 0; tt < 2; ++tt)
            #pragma unroll
            for (int ut = 0; ut < 4; ++ut) acc[tt][ut] = (f32x4){0.f, 0.f, 0.f, 0.f};

        // prologue: A + B for kc=0
        f32x4 fa0 = *(const f32x4*)(a0);
        f32x4 fa1 = *(const f32x4*)(a0 + 4);
        f32x4 fb0 = *(const f32x4*)(a1);
        f32x4 fb1 = *(const f32x4*)(a1 + 4);
        s16x8 bcur[4], bnxt[4];
        #pragma unroll
        for (int ut = 0; ut < 4; ++ut) bcur[ut] = *(const s16x8*)(wb[ut]);

        #pragma unroll
        for (int kc = 0; kc < 8; ++kc) {
            // issue next-kc loads first (stream ahead; TLP covers if sunk)
            f32x4 na0, na1, nb0, nb1;
            if (kc < 7) {
                const int o = (kc + 1) * 32;
                na0 = *(const f32x4*)(a0 + o);
                na1 = *(const f32x4*)(a0 + o + 4);
                nb0 = *(const f32x4*)(a1 + o);
                nb1 = *(const f32x4*)(a1 + o + 4);
                #pragma unroll
                for (int ut = 0; ut < 4; ++ut)
                    bnxt[ut] = *(const s16x8*)(wb[ut] + (kc + 1) * 32);
            }
            union { s16x8 v; unsigned u[4]; } af0, af1;
            af0.u[0] = cvt_pk_bf16(fa0[0], fa0[1]);
            af0.u[1] = cvt_pk_bf16(fa0[2], fa0[3]);
            af0.u[2] = cvt_pk_bf16(fa1[0], fa1[1]);
            af0.u[3] = cvt_pk_bf16(fa1[2], fa1[3]);
            af1.u[0] = cvt_pk_bf16(fb0[0], fb0[1]);
            af1.u[1] = cvt_pk_bf16(fb0[2], fb0[3]);
            af1.u[2] = cvt_pk_bf16(fb1[0], fb1[1]);
            af1.u[3] = cvt_pk_bf16(fb1[2], fb1[3]);
            #pragma unroll
            for (int ut = 0; ut < 4; ++ut)
                acc[0][ut] = __builtin_amdgcn_mfma_f32_16x16x32_bf16(af0.v, bcur[ut], acc[0][ut], 0, 0, 0);
            #pragma unroll
            for (int ut = 0; ut < 4; ++ut)
                acc[1][ut] = __builtin_amdgcn_mfma_f32_16x16x32_bf16(af1.v, bcur[ut], acc[1][ut], 0, 0, 0);
            if (kc < 7) {
                fa0 = na0; fa1 = na1; fb0 = nb0; fb1 = nb1;
                #pragma unroll
                for (int ut = 0; ut < 4; ++ut) bcur[ut] = bnxt[ut];
            }
        }

        // epilogue: tanh·V, reduce over 16 u-lanes (wave-local)
        float psc[2][4];
        #pragma unroll
        for (int tt = 0; tt < 2; ++tt)
            #pragma unroll
            for (int i = 0; i < 4; ++i) psc[tt][i] = 0.f;
        #pragma unroll
        for (int tt = 0; tt < 2; ++tt)
            #pragma unroll
            for (int ut = 0; ut < 4; ++ut)
                #pragma unroll
                for (int i = 0; i < 4; ++i)
                    psc[tt][i] += fast_tanh(acc[tt][ut][i] + qreg[ut]) * Vreg[ut];
        #pragma unroll
        for (int tt = 0; tt < 2; ++tt)
            #pragma unroll
            for (int i = 0; i < 4; ++i) {
                float v = psc[tt][i];
                v += __shfl_xor(v, 1, 64);
                v += __shfl_xor(v, 2, 64);
                v += __shfl_xor(v, 4, 64);
                v += __shfl_xor(v, 8, 64);
                if (l15 == 0) sred[wid][tt * 16 + hi * 4 + i] = v;
            }
        __syncthreads();  // B1

        // wave 0: scores + strip softmax partials + running (M,S)
        if (tid < 64) {
            const int row = lane & 31;
            float s = sred[0][row] + sred[1][row] + sred[2][row] + sred[3][row] + bv;
            if (lane < 32) scores[b * Tn + t0 + row] = s;
            float m = s;
            #pragma unroll
            for (int off = 16; off > 0; off >>= 1) m = fmaxf(m, __shfl_xor(m, off, 64));
            float p = __expf(s - m);
            float S = p;
            #pragma unroll
            for (int off = 16; off > 0; off >>= 1) S += __shfl_xor(S, off, 64);
            if (lane < 32) slp[row] = p;
            if (lane == 0) {
                float Mold = runMS[0];
                float Mnew = fmaxf(Mold, m);
                float sco = __expf(Mold - Mnew);
                float scc = __expf(m - Mnew);
                sfac[0] = sco; sfac[1] = scc;
                runMS[0] = Mnew;
                runMS[1] = runMS[1] * sco + S * scc;
            }
        }
        __syncthreads();  // B2

        // online context from values (L3-hot re-read, perfectly coalesced)
        const float sco = sfac[0], scc = sfac[1];
        const int d4 = (tid & 63) * 4;
        const int tg = tid >> 6;
        f32x4 loc = (f32x4){0.f, 0.f, 0.f, 0.f};
        #pragma unroll
        for (int t = tg; t < 32; t += 4) {
            const float p = slp[t];
            const f32x4 v = *(const f32x4*)(arow + (size_t)t * Dn + d4);
            loc[0] += p * v[0];
            loc[1] += p * v[1];
            loc[2] += p * v[2];
            loc[3] += p * v[3];
        }
        cacc = cacc * sco + loc * scc;
    }

    // block finalize
    const int tg = tid >> 6;
    cred[tg][tid & 63] = cacc;
    __syncthreads();
    if (tg == 0) {
        const f32x4 o = cred[0][tid] + cred[1][tid] + cred[2][tid] + cred[3][tid];
        *(f32x4*)&pctx[((size_t)(b * NBLK + blk)) * Dn + (tid & 63) * 4] = o;
    }
    if (tid == 0) {
        pM[b * NBLK + blk] = runMS[0];
        pS[b * NBLK + blk] = runMS[1];
    }
}

// K2: per-batch flash reduce over NBLK block partials.
__global__ __launch_bounds__(256) void k_reduce(const float* __restrict__ pM,
                                                const float* __restrict__ pS,
                                                const float* __restrict__ pctx,
                                                float* __restrict__ context,
                                                float* __restrict__ MS) {
    const int b = blockIdx.x, d = threadIdx.x;
    float M = -1e30f;
    #pragma unroll 8
    for (int c = 0; c < NBLK; ++c) M = fmaxf(M, pM[b * NBLK + c]);
    float S = 0.f, ctx = 0.f;
    #pragma unroll 4
    for (int c = 0; c < NBLK; ++c) {
        const float w = __expf(pM[b * NBLK + c] - M);
        S += w * pS[b * NBLK + c];
        ctx += w * pctx[((size_t)(b * NBLK + c)) * Dn + d];
    }
    context[b * Dn + d] = __fdividef(ctx, S);
    if (d == 0) { MS[b * 2] = M; MS[b * 2 + 1] = S; }
}

// K3: attn[b,t] = exp(score - M_b) / S_b, in place.
__global__ __launch_bounds__(256) void k_attn(float* __restrict__ attn,
                                              const float* __restrict__ MS) {
    const int b = blockIdx.y;
    const int base = b * Tn + blockIdx.x * 1024 + threadIdx.x * 4;
    const float M = MS[b * 2];
    const float invS = __fdividef(1.0f, MS[b * 2 + 1]);
    float4 s = *(const float4*)&attn[base];
    s.x = __expf(s.x - M) * invS;
    s.y = __expf(s.y - M) * invS;
    s.z = __expf(s.z - M) * invS;
    s.w = __expf(s.w - M) * invS;
    *(float4*)&attn[base] = s;
}

extern "C" void kernel_launch(void* const* d_in, const int* in_sizes, int n_in,
                              void* d_out, int out_size, void* d_ws, size_t ws_size,
                              hipStream_t stream) {
    const float* query  = (const float*)d_in[0];
    const float* values = (const float*)d_in[1];
    const float* W1     = (const float*)d_in[2];
    const float* b1     = (const float*)d_in[3];
    const float* W2     = (const float*)d_in[4];
    const float* b2     = (const float*)d_in[5];
    const float* Vw     = (const float*)d_in[6];
    const float* bV     = (const float*)d_in[7];

    float* context = (float*)d_out;            // [B,D]
    float* attn    = (float*)d_out + Bn * Dn;  // [B,T,1] — raw scores, then attn in place

    float*  pctx = (float*)d_ws;                       // [B, NBLK, D] = 2 MB
    float*  pM   = pctx + (size_t)Bn * NBLK * Dn;      // [B, NBLK]
    float*  pS   = pM + Bn * NBLK;                     // [B, NBLK]
    float*  qb   = pS + Bn * NBLK;                     // [B, U]
    float*  MS   = qb + Bn * Un;                       // [B, 2]
    ushort* W1T  = (ushort*)(MS + Bn * 2);             // [U, D] bf16

    k_prep<<<dim3(256 + Bn), dim3(256), 0, stream>>>(W1, W1T, query, W2, b1, b2, qb);
    k_main<<<dim3(NBLK, Bn), dim3(256), 0, stream>>>(values, W1T, qb, Vw, bV,
                                                     attn, pM, pS, pctx);
    k_reduce<<<dim3(Bn), dim3(256), 0, stream>>>(pM, pS, pctx, context, MS);
    k_attn<<<dim3(Tn / 1024, Bn), dim3(256), 0, stream>>>(attn, MS);
}

// Round 11
// 78.818 us; speedup vs baseline: 1.8820x; 1.8820x over previous
//
#include <hip/hip_runtime.h>
#include <hip/hip_bf16.h>

typedef __attribute__((ext_vector_type(4))) float f32x4;
typedef __attribute__((ext_vector_type(8))) short s16x8;
typedef __attribute__((ext_vector_type(4))) short s16x4;

static constexpr int Bn = 32;
static constexpr int Tn = 4096;
static constexpr int Dn = 256;
static constexpr int Un = 256;
static constexpr int CH = Tn / 64;   // 64 chunks per batch, 1 chunk per block

// HW bf16 cast (RTNE) — compiler emits v_cvt_pk_bf16_f32 pairs, self-scheduled
__device__ __forceinline__ ushort f2bf_hw(float f) {
    union { __hip_bfloat16 h; ushort u; } c;
    c.h = __float2bfloat16(f);
    return c.u;
}
__device__ __forceinline__ float bf2f(ushort u) {
    return __uint_as_float(((unsigned)u) << 16);
}
// 6-inst tanh: 1 - 2/(1+e^{2x}); exact ±1 at saturation, ~1e-6 rel err midrange
__device__ __forceinline__ float tanh5(float x) {
    float t = __expf(2.0f * x);
    return 1.0f - __fdividef(2.0f, 1.0f + t);
}

// K0: prep. Blocks 0..255: W1T[u][d] = bf16(W1[d][u]). Blocks 256..287: qproj.
__global__ __launch_bounds__(256) void k_prep(const float* __restrict__ W1,
                                              ushort* __restrict__ W1T,
                                              const float* __restrict__ query,
                                              const float* __restrict__ W2,
                                              const float* __restrict__ b1,
                                              const float* __restrict__ b2,
                                              float* __restrict__ qb) {
    __shared__ float qs[Dn];
    if (blockIdx.x < 256) {
        const int u = blockIdx.x, d = threadIdx.x;
        W1T[u * Dn + d] = f2bf_hw(W1[d * Un + u]);
    } else {
        const int b = blockIdx.x - 256, u = threadIdx.x;
        qs[u] = query[b * Dn + u];
        __syncthreads();
        float acc = b1[u] + b2[u];
        #pragma unroll 8
        for (int d = 0; d < Dn; ++d) acc += qs[d] * W2[d * Un + u];
        qb[b * Un + u] = acc;
    }
}

// K1: R6 skeleton, instruction-dieted. Block = one 64t x 256u chunk, 4 waves
// (wave owns 64t x 64u, acc[4][4]). A staged once to LDS via HW bf16 cast;
// B streams global->reg depth-2 from L2-hot W1T; zero k-loop barriers.
// Epilogue: 6-inst tanh -> V-dot -> shuffle reduce. Flash section is
// redundantly wave-parallel (no wave0 gating, p stays in registers, context
// gets p via shuffles). 3 barriers total.
__global__ __launch_bounds__(256, 4) void k_fused(const float* __restrict__ values,
                                                  const ushort* __restrict__ W1T,
                                                  const float* __restrict__ qb,
                                                  const float* __restrict__ Vw,
                                                  const float* __restrict__ bV,
                                                  float* __restrict__ scores,
                                                  float* __restrict__ pm,
                                                  float* __restrict__ ps,
                                                  float* __restrict__ pctx) {
    __shared__ __align__(16) ushort Al[64][264];   // 33.8 KB, 528B rows (2-way free)
    __shared__ float sred[4][64];                  // 1 KB
    __shared__ f32x4 cred[4][64];                  // 4 KB
    const int tid = threadIdx.x;
    const int b = blockIdx.y, c = blockIdx.x;
    const int t0 = c * 64;
    const int wid = tid >> 6, lane = tid & 63;
    const int l15 = lane & 15, hi = lane >> 4;

    // stage A: 64 rows x 256 d, fp32 coalesced -> HW bf16 -> LDS
    const float* vbase = values + ((size_t)b * Tn + t0) * Dn;
    #pragma unroll
    for (int i = 0; i < 8; ++i) {
        int flat = i * 2048 + tid * 8;
        int row = flat >> 8, col = flat & 255;
        const float4 f0 = *(const float4*)&vbase[row * Dn + col];
        const float4 f1 = *(const float4*)&vbase[row * Dn + col + 4];
        s16x8 p;
        p[0] = (short)f2bf_hw(f0.x); p[1] = (short)f2bf_hw(f0.y);
        p[2] = (short)f2bf_hw(f0.z); p[3] = (short)f2bf_hw(f0.w);
        p[4] = (short)f2bf_hw(f1.x); p[5] = (short)f2bf_hw(f1.y);
        p[6] = (short)f2bf_hw(f1.z); p[7] = (short)f2bf_hw(f1.w);
        *(s16x8*)&Al[row][col] = p;
    }

    const ushort* wbase = W1T + (size_t)(wid * 64 + l15) * Dn + hi * 8;

    f32x4 acc[4][4];
    #pragma unroll
    for (int tt = 0; tt < 4; ++tt)
        #pragma unroll
        for (int ut = 0; ut < 4; ++ut) acc[tt][ut] = (f32x4){0.f, 0.f, 0.f, 0.f};

    // B prefetch depth 2
    s16x8 bfn0[4], bfn1[4];
    #pragma unroll
    for (int ut = 0; ut < 4; ++ut)
        bfn0[ut] = *(const s16x8*)&wbase[(size_t)ut * 16 * Dn];
    #pragma unroll
    for (int ut = 0; ut < 4; ++ut)
        bfn1[ut] = *(const s16x8*)&wbase[(size_t)ut * 16 * Dn + 32];

    __syncthreads();  // B1: A tile ready

    #pragma unroll
    for (int kc = 0; kc < 8; ++kc) {
        s16x8 bf[4];
        #pragma unroll
        for (int ut = 0; ut < 4; ++ut) { bf[ut] = bfn0[ut]; bfn0[ut] = bfn1[ut]; }
        if (kc < 6) {
            #pragma unroll
            for (int ut = 0; ut < 4; ++ut)
                bfn1[ut] = *(const s16x8*)&wbase[(size_t)ut * 16 * Dn + (kc + 2) * 32];
        }
        const int k0 = kc * 32;
        s16x8 af[4];
        #pragma unroll
        for (int tt = 0; tt < 4; ++tt)
            af[tt] = *(const s16x8*)&Al[tt * 16 + l15][k0 + hi * 8];
        #pragma unroll
        for (int tt = 0; tt < 4; ++tt)
            #pragma unroll
            for (int ut = 0; ut < 4; ++ut)
                acc[tt][ut] = __builtin_amdgcn_mfma_f32_16x16x32_bf16(af[tt], bf[ut], acc[tt][ut], 0, 0, 0);
    }

    // epilogue constants (after k-loop, keeps loop VGPR low)
    float Vreg[4], qreg[4];
    #pragma unroll
    for (int ut = 0; ut < 4; ++ut) {
        int u = wid * 64 + ut * 16 + l15;
        Vreg[ut] = Vw[u];
        qreg[ut] = qb[b * Un + u];
    }

    // acc[tt][ut][i] = proj[t=t0+tt*16+hi*4+i][u=wid*64+ut*16+l15]
    float psc[4][4];
    #pragma unroll
    for (int tt = 0; tt < 4; ++tt)
        #pragma unroll
        for (int i = 0; i < 4; ++i) psc[tt][i] = 0.f;
    #pragma unroll
    for (int tt = 0; tt < 4; ++tt)
        #pragma unroll
        for (int ut = 0; ut < 4; ++ut)
            #pragma unroll
            for (int i = 0; i < 4; ++i)
                psc[tt][i] += tanh5(acc[tt][ut][i] + qreg[ut]) * Vreg[ut];

    #pragma unroll
    for (int tt = 0; tt < 4; ++tt)
        #pragma unroll
        for (int i = 0; i < 4; ++i) {
            float v = psc[tt][i];
            v += __shfl_xor(v, 1, 64);
            v += __shfl_xor(v, 2, 64);
            v += __shfl_xor(v, 4, 64);
            v += __shfl_xor(v, 8, 64);
            if (l15 == 0) sred[wid][tt * 16 + hi * 4 + i] = v;
        }
    __syncthreads();  // B2: sred ready

    // redundant wave-parallel flash: every wave computes identical m, S;
    // lane holds row=lane's score/p in registers (no LDS round-trip).
    float s = sred[0][lane] + sred[1][lane] + sred[2][lane] + sred[3][lane] + bV[0];
    if (wid == 0) scores[b * Tn + t0 + lane] = s;
    float m = s;
    #pragma unroll
    for (int off = 32; off > 0; off >>= 1) m = fmaxf(m, __shfl_xor(m, off, 64));
    const float p = __expf(s - m);
    float S = p;
    #pragma unroll
    for (int off = 32; off > 0; off >>= 1) S += __shfl_xor(S, off, 64);

    // context partial from the bf16 A tile; p[t] via intra-wave shuffle
    const int d4 = lane * 4;
    f32x4 loc = (f32x4){0.f, 0.f, 0.f, 0.f};
    #pragma unroll
    for (int k = 0; k < 16; ++k) {
        const int t = wid + 4 * k;
        const float pk = __shfl(p, t, 64);     // uniform source -> broadcast
        const s16x4 v = *(const s16x4*)&Al[t][d4];
        loc[0] += pk * bf2f((ushort)v[0]);
        loc[1] += pk * bf2f((ushort)v[1]);
        loc[2] += pk * bf2f((ushort)v[2]);
        loc[3] += pk * bf2f((ushort)v[3]);
    }
    cred[wid][lane] = loc;
    __syncthreads();  // B3: cred ready
    if (wid == 0) {
        const f32x4 o = cred[0][lane] + cred[1][lane] + cred[2][lane] + cred[3][lane];
        *(f32x4*)&pctx[((size_t)(b * CH + c)) * Dn + d4] = o;
    }
    if (tid == 0) { pm[b * CH + c] = m; ps[b * CH + c] = S; }
}

// K2: per-batch flash reduce over CH chunk partials.
__global__ __launch_bounds__(256) void k_reduce(const float* __restrict__ pm,
                                                const float* __restrict__ ps,
                                                const float* __restrict__ pctx,
                                                float* __restrict__ context,
                                                float* __restrict__ MS) {
    const int b = blockIdx.x, d = threadIdx.x;
    float M = -1e30f;
    #pragma unroll 8
    for (int c = 0; c < CH; ++c) M = fmaxf(M, pm[b * CH + c]);
    float S = 0.f, ctx = 0.f;
    #pragma unroll 4
    for (int c = 0; c < CH; ++c) {
        const float w = __expf(pm[b * CH + c] - M);
        S += w * ps[b * CH + c];
        ctx += w * pctx[((size_t)(b * CH + c)) * Dn + d];
    }
    context[b * Dn + d] = __fdividef(ctx, S);
    if (d == 0) { MS[b * 2] = M; MS[b * 2 + 1] = S; }
}

// K3: attn[b,t] = exp(score - M_b) / S_b, in place.
__global__ __launch_bounds__(256) void k_attn(float* __restrict__ attn,
                                              const float* __restrict__ MS) {
    const int b = blockIdx.y;
    const int base = b * Tn + blockIdx.x * 1024 + threadIdx.x * 4;
    const float M = MS[b * 2];
    const float invS = __fdividef(1.0f, MS[b * 2 + 1]);
    float4 s = *(const float4*)&attn[base];
    s.x = __expf(s.x - M) * invS;
    s.y = __expf(s.y - M) * invS;
    s.z = __expf(s.z - M) * invS;
    s.w = __expf(s.w - M) * invS;
    *(float4*)&attn[base] = s;
}

extern "C" void kernel_launch(void* const* d_in, const int* in_sizes, int n_in,
                              void* d_out, int out_size, void* d_ws, size_t ws_size,
                              hipStream_t stream) {
    const float* query  = (const float*)d_in[0];
    const float* values = (const float*)d_in[1];
    const float* W1     = (const float*)d_in[2];
    const float* b1     = (const float*)d_in[3];
    const float* W2     = (const float*)d_in[4];
    const float* b2     = (const float*)d_in[5];
    const float* Vw     = (const float*)d_in[6];
    const float* bV     = (const float*)d_in[7];

    float* context = (float*)d_out;            // [B,D]
    float* attn    = (float*)d_out + Bn * Dn;  // [B,T,1] — raw scores, then attn in place

    float*  pctx = (float*)d_ws;                       // [B, CH, D] = 2 MB
    float*  pm   = pctx + (size_t)Bn * CH * Dn;        // [B, CH]
    float*  ps   = pm + Bn * CH;                       // [B, CH]
    float*  qb   = ps + Bn * CH;                       // [B, U]
    float*  MS   = qb + Bn * Un;                       // [B, 2]
    ushort* W1T  = (ushort*)(MS + Bn * 2);             // [U, D] bf16

    k_prep<<<dim3(256 + Bn), dim3(256), 0, stream>>>(W1, W1T, query, W2, b1, b2, qb);
    k_fused<<<dim3(CH, Bn), dim3(256), 0, stream>>>(values, W1T, qb, Vw, bV,
                                                    attn, pm, ps, pctx);
    k_reduce<<<dim3(Bn), dim3(256), 0, stream>>>(pm, ps, pctx, context, MS);
    k_attn<<<dim3(Tn / 1024, Bn), dim3(256), 0, stream>>>(attn, MS);
}